// Round 4
// baseline (2455.734 us; speedup 1.0000x reference)
//
#include <hip/hip_runtime.h>
#include <cstdint>
#include <cstddef>

// Problem: B=64, T=512, D_IN=1024, UNITS=1024
//   phase 1: xk = x @ kernel  -> written into d_out  [32768 x 1024]
//   phase 2: persistent scan kernel, in-place on d_out:
//            h_t = relu(xk_t + h_{t-1} @ R)
//
// Phase-2 geometry: 4 clusters (16 batches = one MFMA M-tile each)
//                   x 32 col-group WGs (32 cols each) = 128 WGs, 256 thr.
// R4: fully decoupled waves. Per-WAVE flag stores (value=t+1, own CP slot)
// replace the serialized 32-atomic fan-in; every wave polls all 128 cluster
// wave-flags with a 64-lane gather + ballot. Zero __syncthreads around the
// barrier (only the LDS k-reduce sync remains, reduce buffer parity-double-
// buffered). xk prefetched before the poll; 4 MFMA accumulators halve the
// dependent chain. No cache-maintenance instructions anywhere.

typedef __attribute__((ext_vector_type(8))) short short8;
typedef __attribute__((ext_vector_type(4))) float f32x4;

static __device__ __forceinline__ unsigned short f2bf_rne(float f) {
  unsigned u = __float_as_uint(f);
  u += 0x7fffu + ((u >> 16) & 1u);
  return (unsigned short)(u >> 16);
}

static __device__ __forceinline__ void st_g16_cc(unsigned short* p, unsigned short val) {
  unsigned v32 = val;
  asm volatile("global_store_short %0, %1, off sc0 sc1"
               :: "v"(p), "v"(v32) : "memory");
}
static __device__ __forceinline__ void wait_vm0() {
  asm volatile("s_waitcnt vmcnt(0)" ::: "memory");
}
static __device__ __forceinline__ void st_flag_cc(unsigned int* p, unsigned val) {
  asm volatile("global_store_dword %0, %1, off sc0 sc1"
               :: "v"(p), "v"(val) : "memory");
}
static __device__ __forceinline__ void ld2_flag_cc(const unsigned int* p0,
                                                   const unsigned int* p1,
                                                   unsigned& f0, unsigned& f1) {
  asm volatile("global_load_dword %0, %2, off sc0 sc1\n\t"
               "global_load_dword %1, %3, off sc0 sc1\n\t"
               "s_waitcnt vmcnt(0)"
               : "=&v"(f0), "=&v"(f1) : "v"(p0), "v"(p1) : "memory");
}

// ---------------------------------------------------------------- phase 1
__global__ __launch_bounds__(256) void xproj_kernel(const float* __restrict__ x,
                                                    const float* __restrict__ kern,
                                                    float* __restrict__ out) {
  __shared__ unsigned short Abuf[128 * 40];
  __shared__ unsigned short Bbuf[128 * 40];
  const int tid = threadIdx.x;
  const int lane = tid & 63;
  const int wv = tid >> 6;
  const int q = lane >> 4;
  const int lr = lane & 15;
  const int wm = (wv >> 1) * 64;
  const int wn = (wv & 1) * 64;
  const long rowbase = (long)blockIdx.y * 128;
  const int colbase = blockIdx.x * 128;

  f32x4 acc[4][4];
#pragma unroll
  for (int i = 0; i < 4; i++)
#pragma unroll
    for (int j = 0; j < 4; j++) acc[i][j] = (f32x4)0.f;

  for (int kb = 0; kb < 1024; kb += 32) {
#pragma unroll
    for (int r = 0; r < 4; ++r) {
      int idx = tid + r * 256;
      int m = idx >> 3;
      int kk = (idx & 7) * 4;
      float4 v = *(const float4*)(x + (rowbase + m) * 1024 + kb + kk);
      ushort4 w4;
      w4.x = f2bf_rne(v.x); w4.y = f2bf_rne(v.y);
      w4.z = f2bf_rne(v.z); w4.w = f2bf_rne(v.w);
      *(ushort4*)&Abuf[m * 40 + kk] = w4;
    }
#pragma unroll
    for (int r = 0; r < 4; ++r) {
      int idx = tid + r * 256;
      int kr = idx >> 5;
      int nn = (idx & 31) * 4;
      float4 v = *(const float4*)(kern + (long)(kb + kr) * 1024 + colbase + nn);
      Bbuf[(nn + 0) * 40 + kr] = f2bf_rne(v.x);
      Bbuf[(nn + 1) * 40 + kr] = f2bf_rne(v.y);
      Bbuf[(nn + 2) * 40 + kr] = f2bf_rne(v.z);
      Bbuf[(nn + 3) * 40 + kr] = f2bf_rne(v.w);
    }
    __syncthreads();
    short8 af[4], bfr[4];
#pragma unroll
    for (int i = 0; i < 4; i++)
      af[i] = *(const short8*)&Abuf[(wm + i * 16 + lr) * 40 + q * 8];
#pragma unroll
    for (int j = 0; j < 4; j++)
      bfr[j] = *(const short8*)&Bbuf[(wn + j * 16 + lr) * 40 + q * 8];
#pragma unroll
    for (int i = 0; i < 4; i++)
#pragma unroll
      for (int j = 0; j < 4; j++)
        acc[i][j] = __builtin_amdgcn_mfma_f32_16x16x32_bf16(af[i], bfr[j], acc[i][j], 0, 0, 0);
    __syncthreads();
  }
#pragma unroll
  for (int i = 0; i < 4; i++) {
#pragma unroll
    for (int r = 0; r < 4; r++) {
      long row = rowbase + wm + i * 16 + q * 4 + r;
      float* op = out + row * 1024 + colbase + wn + lr;
#pragma unroll
      for (int j = 0; j < 4; j++) op[j * 16] = acc[i][j][r];
    }
  }
}

// ---------------------------------------------------------------- phase 2
// hbuf layout (u16): [parity 2][part hi/lo 2][cluster 4][16384]
//   element (m,k) at (k>>3)*128 + m*8 + (k&7)  -> A-frag dwordx4-ready.
// flags: per cluster 128 wave-slots (wg*4+wv), 16B stride, value = t+1.
__global__ __launch_bounds__(256) void rnn_scan_kernel(const float* __restrict__ R,
                                                       float* __restrict__ out,
                                                       unsigned short* __restrict__ hbuf,
                                                       unsigned int* __restrict__ flags) {
  const int tid = threadIdx.x;
  const int lane = tid & 63;
  const int wv = tid >> 6;        // k-quarter 0..3
  const int q = lane >> 4;
  const int lr = lane & 15;
  const int cluster = blockIdx.x & 3;
  const int cg = blockIdx.x >> 2; // col-group 0..31

  // persistent W fragments: B[k][n] frag: lane n=lr, k = q*8+j
  short8 w[2][8];
#pragma unroll
  for (int nt = 0; nt < 2; nt++) {
    int col = cg * 32 + nt * 16 + lr;
#pragma unroll
    for (int cc = 0; cc < 8; cc++) {
      int k0 = wv * 256 + cc * 32 + q * 8;
      short8 t8;
#pragma unroll
      for (int j = 0; j < 8; j++)
        t8[j] = (short)f2bf_rne(R[(long)(k0 + j) * 1024 + col]);
      w[nt][cc] = t8;
    }
  }

  __shared__ float red[2][4 * 2 * 64 * 4];  // parity-double-buffered, 16 KB
  unsigned int* cflags = flags + cluster * 512;          // 128 slots x 16B
  unsigned int* myflag = cflags + (cg * 4 + wv) * 4;     // this wave's slot
  const unsigned int* pf0 = cflags + lane * 4;           // slots 0..63
  const unsigned int* pf1 = cflags + (lane + 64) * 4;    // slots 64..127
  const int m_lo = tid >> 5;   // 0..7
  const int myn = tid & 31;
  const int off0 = (wv * 32 + q) * 128 + lr * 8;  // cc=0 frag offset (u16)

  for (int t = 0; t < 512; ++t) {
    // ---- xk prefetch (independent of h; pinned before the poll asm) ----
    float xk[2];
#pragma unroll
    for (int mi = 0; mi < 2; ++mi) {
      int m = m_lo + mi * 8;
      long orow = (long)(cluster * 16 + m) * 512 + t;
      xk[mi] = out[orow * 1024 + cg * 32 + myn];
    }

    f32x4 acc0 = (f32x4)0.f, acc1 = (f32x4)0.f;
    if (t > 0) {
      // ---- wait for all 128 cluster waves to have finished step t-1 ----
      const unsigned tgt = (unsigned)t;
      for (;;) {
        unsigned f0, f1;
        ld2_flag_cc(pf0, pf1, f0, f1);
        if (__all((f0 >= tgt) & (f1 >= tgt))) break;
      }
      // ---- coherent h_{t-1} fragment loads (fused waitcnt) ----
      const unsigned short* hb = hbuf + (size_t)((((t - 1) & 1) * 2 + 0) * 4 + cluster) * 16384;
      const unsigned short* lb = hbuf + (size_t)((((t - 1) & 1) * 2 + 1) * 4 + cluster) * 16384;
      const unsigned short* a0 = hb + off0;
      const unsigned short* a4 = a0 + 2048;
      const unsigned short* b0 = lb + off0;
      const unsigned short* b4 = b0 + 2048;
      short8 ah[8], al[8];
      asm volatile(
          "global_load_dwordx4 %0,  %16, off sc0 sc1\n\t"
          "global_load_dwordx4 %1,  %16, off offset:1024 sc0 sc1\n\t"
          "global_load_dwordx4 %2,  %16, off offset:2048 sc0 sc1\n\t"
          "global_load_dwordx4 %3,  %16, off offset:3072 sc0 sc1\n\t"
          "global_load_dwordx4 %4,  %17, off sc0 sc1\n\t"
          "global_load_dwordx4 %5,  %17, off offset:1024 sc0 sc1\n\t"
          "global_load_dwordx4 %6,  %17, off offset:2048 sc0 sc1\n\t"
          "global_load_dwordx4 %7,  %17, off offset:3072 sc0 sc1\n\t"
          "global_load_dwordx4 %8,  %18, off sc0 sc1\n\t"
          "global_load_dwordx4 %9,  %18, off offset:1024 sc0 sc1\n\t"
          "global_load_dwordx4 %10, %18, off offset:2048 sc0 sc1\n\t"
          "global_load_dwordx4 %11, %18, off offset:3072 sc0 sc1\n\t"
          "global_load_dwordx4 %12, %19, off sc0 sc1\n\t"
          "global_load_dwordx4 %13, %19, off offset:1024 sc0 sc1\n\t"
          "global_load_dwordx4 %14, %19, off offset:2048 sc0 sc1\n\t"
          "global_load_dwordx4 %15, %19, off offset:3072 sc0 sc1\n\t"
          "s_waitcnt vmcnt(0)"
          : "=&v"(ah[0]), "=&v"(ah[1]), "=&v"(ah[2]), "=&v"(ah[3]),
            "=&v"(ah[4]), "=&v"(ah[5]), "=&v"(ah[6]), "=&v"(ah[7]),
            "=&v"(al[0]), "=&v"(al[1]), "=&v"(al[2]), "=&v"(al[3]),
            "=&v"(al[4]), "=&v"(al[5]), "=&v"(al[6]), "=&v"(al[7])
          : "v"(a0), "v"(a4), "v"(b0), "v"(b4)
          : "memory");
      // 4 independent accumulator chains (depth 8 each)
      f32x4 a0h = (f32x4)0.f, a0l = (f32x4)0.f, a1h = (f32x4)0.f, a1l = (f32x4)0.f;
#pragma unroll
      for (int cc = 0; cc < 8; cc++) {
        a0h = __builtin_amdgcn_mfma_f32_16x16x32_bf16(ah[cc], w[0][cc], a0h, 0, 0, 0);
        a0l = __builtin_amdgcn_mfma_f32_16x16x32_bf16(al[cc], w[0][cc], a0l, 0, 0, 0);
        a1h = __builtin_amdgcn_mfma_f32_16x16x32_bf16(ah[cc], w[1][cc], a1h, 0, 0, 0);
        a1l = __builtin_amdgcn_mfma_f32_16x16x32_bf16(al[cc], w[1][cc], a1l, 0, 0, 0);
      }
      acc0 = a0h + a0l;
      acc1 = a1h + a1l;
    }
    // ---- 4-way k-split reduction through parity-buffered LDS ----
    float* rp = red[t & 1];
    *(f32x4*)&rp[((wv * 2 + 0) * 64 + lane) * 4] = acc0;
    *(f32x4*)&rp[((wv * 2 + 1) * 64 + lane) * 4] = acc1;
    __syncthreads();
#pragma unroll
    for (int mi = 0; mi < 2; ++mi) {
      int m = m_lo + mi * 8;
      int nt = myn >> 4;
      int ln = (myn & 15) + ((m >> 2) & 3) * 16;
      int r = m & 3;
      float s = rp[((0 * 2 + nt) * 64 + ln) * 4 + r] + rp[((1 * 2 + nt) * 64 + ln) * 4 + r] +
                rp[((2 * 2 + nt) * 64 + ln) * 4 + r] + rp[((3 * 2 + nt) * 64 + ln) * 4 + r];
      long orow = (long)(cluster * 16 + m) * 512 + t;
      float* op = out + orow * 1024 + cg * 32 + myn;
      float h = s + xk[mi];
      h = fmaxf(h, 0.0f);
      *op = h;                    // final output h_t, in place (plain, cached)
      unsigned short hi = f2bf_rne(h);
      float hf = __uint_as_float(((unsigned)hi) << 16);
      unsigned short lo = f2bf_rne(h - hf);
      int k = cg * 32 + myn;
      int off = (k >> 3) * 128 + m * 8 + (k & 7);
      st_g16_cc(hbuf + (size_t)(((t & 1) * 2 + 0) * 4 + cluster) * 16384 + off, hi);
      st_g16_cc(hbuf + (size_t)(((t & 1) * 2 + 1) * 4 + cluster) * 16384 + off, lo);
    }
    if (t < 511) {
      wait_vm0();                 // this wave's h stores done at CP
      if (lane == 0) st_flag_cc(myflag, (unsigned)(t + 1));
      // no syncthreads: waves decouple until next step's LDS reduce sync
    }
  }
}

extern "C" void kernel_launch(void* const* d_in, const int* in_sizes, int n_in,
                              void* d_out, int out_size, void* d_ws, size_t ws_size,
                              hipStream_t stream) {
  const float* x = (const float*)d_in[0];
  const float* kern = (const float*)d_in[1];
  const float* R = (const float*)d_in[2];
  float* out = (float*)d_out;

  // ws: [0, 512KB) h ping-pong hi/lo buffers; [512KB, +8KB) wave flags
  unsigned short* hbuf = (unsigned short*)d_ws;
  unsigned int* flags = (unsigned int*)((char*)d_ws + (size_t)2 * 2 * 4 * 16384 * sizeof(unsigned short));
  hipMemsetAsync(flags, 0, 8192, stream);

  dim3 g1(8, 256), b1(256);
  xproj_kernel<<<g1, b1, 0, stream>>>(x, kern, out);
  rnn_scan_kernel<<<128, 256, 0, stream>>>(R, out, hbuf, flags);
}